// Round 3
// baseline (169.834 us; speedup 1.0000x reference)
//
#include <hip/hip_runtime.h>

#define N_NODES 100000
#define DEG 16
#define D_FEAT 64
// 16 lanes cooperate on one row; each lane owns one float4 (16B) of the 256B row.

__global__ __launch_bounds__(256) void spmm_hop_kernel(
    const float4* __restrict__ x4,      // [N_NODES * 16] float4
    const float*  __restrict__ values,  // [N_EDGES]
    const int*    __restrict__ indices, // [N_EDGES]
    float4*       __restrict__ out4)    // [N_NODES * 16] float4
{
    const int tid  = blockIdx.x * blockDim.x + threadIdx.x;
    const int row  = tid >> 4;
    const int lane = tid & 15;
    if (row >= N_NODES) return;

    // Coalesced edge loads: lane j holds edge j's (index, value).
    const int   my_idx = indices[row * DEG + lane];
    const float my_val = values[row * DEG + lane];

    // Pre-shuffle all 16 indices (ds_bpermute) so the gather section is pure VMEM.
    int i0  = __shfl(my_idx,  0, 16), i1  = __shfl(my_idx,  1, 16);
    int i2  = __shfl(my_idx,  2, 16), i3  = __shfl(my_idx,  3, 16);
    int i4  = __shfl(my_idx,  4, 16), i5  = __shfl(my_idx,  5, 16);
    int i6  = __shfl(my_idx,  6, 16), i7  = __shfl(my_idx,  7, 16);
    int i8  = __shfl(my_idx,  8, 16), i9  = __shfl(my_idx,  9, 16);
    int i10 = __shfl(my_idx, 10, 16), i11 = __shfl(my_idx, 11, 16);
    int i12 = __shfl(my_idx, 12, 16), i13 = __shfl(my_idx, 13, 16);
    int i14 = __shfl(my_idx, 14, 16), i15 = __shfl(my_idx, 15, 16);

    // Issue ALL 16 gathers; sched_barrier(0) forbids the scheduler from
    // sinking them to their uses (round-2 showed it otherwise will: VGPR=36).
#define G(J) float4 g##J = x4[(unsigned)i##J * 16u + (unsigned)lane];
    G(0) G(1) G(2) G(3) G(4) G(5) G(6) G(7)
    G(8) G(9) G(10) G(11) G(12) G(13) G(14) G(15)
#undef G
    __builtin_amdgcn_sched_barrier(0);

    float4 acc = make_float4(0.f, 0.f, 0.f, 0.f);
#define F(J) { const float v = __shfl(my_val, J, 16); \
               acc.x += v * g##J.x; acc.y += v * g##J.y; \
               acc.z += v * g##J.z; acc.w += v * g##J.w; }
    F(0) F(1) F(2) F(3) F(4) F(5) F(6) F(7)
    F(8) F(9) F(10) F(11) F(12) F(13) F(14) F(15)
#undef F

    out4[(size_t)row * 16 + lane] = acc;
}

extern "C" void kernel_launch(void* const* d_in, const int* in_sizes, int n_in,
                              void* d_out, int out_size, void* d_ws, size_t ws_size,
                              hipStream_t stream) {
    const float* x       = (const float*)d_in[0];  // [N_NODES, 64] f32
    const float* values  = (const float*)d_in[1];  // [N_EDGES] f32
    // d_in[2] = indptr (degenerate fixed-degree CSR) — unused
    const int*   indices = (const int*)d_in[3];    // [N_EDGES] int32

    float* out = (float*)d_out;
    float* ws  = (float*)d_ws;

    const int threads = N_NODES * 16;
    const int block   = 256;
    const int grid    = (threads + block - 1) / block;

    spmm_hop_kernel<<<grid, block, 0, stream>>>((const float4*)x,   values, indices, (float4*)out);
    spmm_hop_kernel<<<grid, block, 0, stream>>>((const float4*)out, values, indices, (float4*)ws);
    spmm_hop_kernel<<<grid, block, 0, stream>>>((const float4*)ws,  values, indices, (float4*)out);
}

// Round 4
// 168.134 us; speedup vs baseline: 1.0101x; 1.0101x over previous
//
#include <hip/hip_runtime.h>

#define N_NODES 100000
#define DEG 16
// D=64 f32 = 256B per row; 16 lanes/row, each lane owns one 16B float4.
// grid*block = 100000*16 = 1,600,000 = 6250 * 256 exactly -> no guard needed.

typedef float v4f __attribute__((ext_vector_type(4)));

__global__ __launch_bounds__(256) void spmm_hop_kernel(
    const float* __restrict__ x,        // [N_NODES * 64] f32 (row = 256 B)
    const float* __restrict__ values,   // [N_EDGES]
    const int*   __restrict__ indices,  // [N_EDGES]
    v4f*         __restrict__ out4)     // [N_NODES * 16] float4
{
    const int tid  = blockIdx.x * blockDim.x + threadIdx.x;
    const int row  = tid >> 4;
    const int lane = tid & 15;

    // Coalesced edge loads: lane j holds edge j's (index, value).
    const int   my_idx = indices[row * DEG + lane];
    const float my_val = values[row * DEG + lane];

    // Byte offsets for all 16 gathers (idx*256 + lane*16; max 25.6MB < 2^32).
    const unsigned lb = (unsigned)lane * 16u;
#define OFF(J) const unsigned o##J = ((unsigned)__shfl(my_idx, J, 16)) * 256u + lb;
    OFF(0)  OFF(1)  OFF(2)  OFF(3)  OFF(4)  OFF(5)  OFF(6)  OFF(7)
    OFF(8)  OFF(9)  OFF(10) OFF(11) OFF(12) OFF(13) OFF(14) OFF(15)
#undef OFF

    // Issue ALL 16 gathers as black-box asm: the compiler cannot sink these
    // to their uses (it did in rounds 1-3: VGPR stayed 32-36, fully
    // latency-serialized at ~700ns per gather = 11us per wave).
    v4f g0, g1, g2, g3, g4, g5, g6, g7, g8, g9, g10, g11, g12, g13, g14, g15;
#define LD(J) asm volatile("global_load_dwordx4 %0, %1, %2" \
                           : "=v"(g##J) : "v"(o##J), "s"(x));
    LD(0)  LD(1)  LD(2)  LD(3)  LD(4)  LD(5)  LD(6)  LD(7)
    LD(8)  LD(9)  LD(10) LD(11) LD(12) LD(13) LD(14) LD(15)
#undef LD

    // Value broadcasts (ds_bpermute) overlap with the 16 in-flight loads.
#define VV(J) const float v##J = __shfl(my_val, J, 16);
    VV(0)  VV(1)  VV(2)  VV(3)  VV(4)  VV(5)  VV(6)  VV(7)
    VV(8)  VV(9)  VV(10) VV(11) VV(12) VV(13) VV(14) VV(15)
#undef VV

    // Drain all 16 loads, then fence the scheduler so no FMA is hoisted
    // above the waitcnt (rule #18: data-deps alone don't order past asm).
    asm volatile("s_waitcnt vmcnt(0)" ::: "memory");
    __builtin_amdgcn_sched_barrier(0);

    v4f acc = {0.f, 0.f, 0.f, 0.f};
#define F(J) acc += g##J * v##J;
    F(0)  F(1)  F(2)  F(3)  F(4)  F(5)  F(6)  F(7)
    F(8)  F(9)  F(10) F(11) F(12) F(13) F(14) F(15)
#undef F

    out4[(size_t)row * 16 + lane] = acc;
}

extern "C" void kernel_launch(void* const* d_in, const int* in_sizes, int n_in,
                              void* d_out, int out_size, void* d_ws, size_t ws_size,
                              hipStream_t stream) {
    const float* x       = (const float*)d_in[0];  // [N_NODES, 64] f32
    const float* values  = (const float*)d_in[1];  // [N_EDGES] f32
    // d_in[2] = indptr (degenerate fixed-degree CSR) — unused
    const int*   indices = (const int*)d_in[3];    // [N_EDGES] int32

    float* out = (float*)d_out;
    float* ws  = (float*)d_ws;

    const int grid  = (N_NODES * 16) / 256;   // 6250, exact
    const int block = 256;

    spmm_hop_kernel<<<grid, block, 0, stream>>>(x,   values, indices, (v4f*)out);
    spmm_hop_kernel<<<grid, block, 0, stream>>>(out, values, indices, (v4f*)ws);
    spmm_hop_kernel<<<grid, block, 0, stream>>>((const float*)ws, values, indices, (v4f*)out);
}

// Round 5
// 89.207 us; speedup vs baseline: 1.9038x; 1.8848x over previous
//
#include <hip/hip_runtime.h>

#define N_NODES 100000
#define DEG 16
// fp16 pipeline: row = 64 halfs = 128 B; 16 lanes/row, each lane owns 4 feats (8 B).
// Working set for gathers: 12.8 MB (vs 25.6 f32) -> better per-XCD L2 residency,
// and half the request/fill bytes on the saturated gather path.

typedef _Float16 half_t;
typedef half_t h4 __attribute__((ext_vector_type(4)));
typedef float  v4f __attribute__((ext_vector_type(4)));

// ---- convert: f32 x -> fp16 buffer ----
__global__ __launch_bounds__(256) void cvt_f32_to_h(
    const v4f* __restrict__ x4, h4* __restrict__ xh)
{
    const int tid = blockIdx.x * blockDim.x + threadIdx.x;  // 1.6M threads, exact
    const v4f v = x4[tid];
    h4 h;
    h.x = (half_t)v.x; h.y = (half_t)v.y; h.z = (half_t)v.z; h.w = (half_t)v.w;
    xh[tid] = h;
}

// ---- hop: fp16 in, fp16 out (f32 accumulate) ----
__global__ __launch_bounds__(256) void hop_h2h(
    const h4*    __restrict__ xh,       // [N_NODES * 16] h4
    const float* __restrict__ values,   // [N_EDGES]
    const int*   __restrict__ indices,  // [N_EDGES]
    h4*          __restrict__ outh)     // [N_NODES * 16] h4
{
    const int tid  = blockIdx.x * blockDim.x + threadIdx.x;
    const int row  = tid >> 4;
    const int lane = tid & 15;

    const int   my_idx = indices[row * DEG + lane];   // coalesced
    const float my_val = values[row * DEG + lane];    // coalesced

    v4f acc = {0.f, 0.f, 0.f, 0.f};
    #pragma unroll
    for (int j = 0; j < DEG; ++j) {
        const int   idx = __shfl(my_idx, j, 16);
        const float v   = __shfl(my_val, j, 16);
        const h4 hv = xh[idx * 16 + lane];            // 8B load, 128B/row coalesced
        acc.x += v * (float)hv.x;
        acc.y += v * (float)hv.y;
        acc.z += v * (float)hv.z;
        acc.w += v * (float)hv.w;
    }
    h4 ho;
    ho.x = (half_t)acc.x; ho.y = (half_t)acc.y;
    ho.z = (half_t)acc.z; ho.w = (half_t)acc.w;
    outh[row * 16 + lane] = ho;
}

// ---- final hop: fp16 in, f32 out ----
__global__ __launch_bounds__(256) void hop_h2f(
    const h4*    __restrict__ xh,
    const float* __restrict__ values,
    const int*   __restrict__ indices,
    v4f*         __restrict__ out4)     // [N_NODES * 16] float4
{
    const int tid  = blockIdx.x * blockDim.x + threadIdx.x;
    const int row  = tid >> 4;
    const int lane = tid & 15;

    const int   my_idx = indices[row * DEG + lane];
    const float my_val = values[row * DEG + lane];

    v4f acc = {0.f, 0.f, 0.f, 0.f};
    #pragma unroll
    for (int j = 0; j < DEG; ++j) {
        const int   idx = __shfl(my_idx, j, 16);
        const float v   = __shfl(my_val, j, 16);
        const h4 hv = xh[idx * 16 + lane];
        acc.x += v * (float)hv.x;
        acc.y += v * (float)hv.y;
        acc.z += v * (float)hv.z;
        acc.w += v * (float)hv.w;
    }
    out4[row * 16 + lane] = acc;                      // 16B/lane, 256B/row coalesced
}

extern "C" void kernel_launch(void* const* d_in, const int* in_sizes, int n_in,
                              void* d_out, int out_size, void* d_ws, size_t ws_size,
                              hipStream_t stream) {
    const float* x       = (const float*)d_in[0];  // [N_NODES, 64] f32
    const float* values  = (const float*)d_in[1];  // [N_EDGES] f32
    // d_in[2] = indptr (degenerate fixed-degree CSR) — unused
    const int*   indices = (const int*)d_in[3];    // [N_EDGES] int32

    v4f* out = (v4f*)d_out;

    // ws layout: two fp16 ping-pong buffers of 12.8 MB each (offset 12.8e6 B,
    // 256B-aligned: 12,800,000 / 256 = 50,000).
    h4* bufA = (h4*)d_ws;
    h4* bufB = (h4*)((char*)d_ws + (size_t)N_NODES * 64 * sizeof(half_t));

    const int block = 256;
    const int grid  = (N_NODES * 16) / block;   // 6250, exact

    // x (f32) -> bufA (fp16)
    cvt_f32_to_h<<<grid, block, 0, stream>>>((const v4f*)x, bufA);
    // hop 1: bufA -> bufB
    hop_h2h<<<grid, block, 0, stream>>>(bufA, values, indices, bufB);
    // hop 2: bufB -> bufA
    hop_h2h<<<grid, block, 0, stream>>>(bufB, values, indices, bufA);
    // hop 3: bufA -> d_out (f32)
    hop_h2f<<<grid, block, 0, stream>>>(bufA, values, indices, out);
}